// Round 6
// baseline (489.057 us; speedup 1.0000x reference)
//
#include <hip/hip_runtime.h>
#include <math.h>

#define B_ 8
#define T_ 2048
#define D_ 2048
#define H_ 128
#define M_ (B_ * T_)

typedef __bf16 bf16x8 __attribute__((ext_vector_type(8)));
typedef __bf16 bf16x4 __attribute__((ext_vector_type(4)));
typedef float f32x4 __attribute__((ext_vector_type(4)));

#define MFMA(a, b, c) __builtin_amdgcn_mfma_f32_16x16x32_bf16(a, b, c, 0, 0, 0)

// ws layout (bf16 elements)
#define QH_OFF 0
#define QL_OFF (1 * 2097152)  // M_*H_
#define KH_OFF (2 * 2097152)
#define KL_OFF (3 * 2097152)
#define VT_OFF (4 * 2097152)        // vt[b][h][t]
#define WTH_OFF (5 * 2097152)       // wt_hi[z*128+n][k]
#define WTL_OFF (WTH_OFF + 786432)  // 3*128*2048

// ---------------- prep: W[k][n] fp32 -> Wt_hi/lo[n][k] bf16 ----------------
__global__ __launch_bounds__(256) void prep_kernel(
    const float* __restrict__ Wq, const float* __restrict__ Wk,
    const float* __restrict__ Wv, __bf16* __restrict__ wt_hi,
    __bf16* __restrict__ wt_lo) {
  const int z = blockIdx.y;
  const int k0 = blockIdx.x * 64;
  const float* W = z == 0 ? Wq : z == 1 ? Wk : Wv;
  __shared__ float tile[64][132];
  const int t = threadIdx.x;
#pragma unroll
  for (int it = 0; it < 8; ++it) {
    int f4 = it * 256 + t;  // 2048 float4 = 64 rows x 32
    int row = f4 >> 5, c = (f4 & 31) << 2;
    *(float4*)&tile[row][c] = *(const float4*)&W[(size_t)(k0 + row) * H_ + c];
  }
  __syncthreads();
  int n = t >> 1, kh = (t & 1) << 5;
  __bf16 h[32], l[32];
#pragma unroll
  for (int kk = 0; kk < 32; ++kk) {
    float x = tile[kh + kk][n];
    __bf16 hi = (__bf16)x;
    h[kk] = hi;
    l[kk] = (__bf16)(x - (float)hi);
  }
  size_t base = (size_t)(z * H_ + n) * D_ + k0 + kh;
#pragma unroll
  for (int c = 0; c < 4; ++c) {
    *(bf16x8*)&wt_hi[base + c * 8] = *(bf16x8*)&h[c * 8];
    *(bf16x8*)&wt_lo[base + c * 8] = *(bf16x8*)&l[c * 8];
  }
}

// ---------------- proj: X-in-LDS, W-direct-from-L2, split-bf16 MFMA --------
// v4: 512 blocks x 512 thr (8 waves). Block = 64m x 192n (n-half = bi&1).
// Round-5 PMC showed the DS pipe was the pole (per wave-kstep: 12 b64 B-frag
// reads + 8 b64 staging writes + 4 b128 A reads ~ 200 cyc vs 90 cyc MFMA;
// MfmaUtil pinned at 23% while occupancy doubled). W's B-fragment is directly
// loadable from the wt[n][k] layout (contiguous bf16x8) and the per-XCD
// W-half (1.6MB, parity-mapped) is L2-resident -> drop W from LDS entirely,
// reg-double-buffer next kstep's 6 fragments during current MFMA. LDS now
// only X (9.2KB). DS-pipe cost drops ~2.6x; B-frag LDS bank conflicts gone.
// Numerics bit-identical (same fragment values, same MFMA order).
#define XSTR 72  // X row-pair stride (32 hi | 32 lo | 8 pad) = 144 B

#define PROJ_STEP(KS, CH, CL, NH, NL)                                     \
  {                                                                       \
    __syncthreads();                                                      \
    {                                                                     \
      __bf16 h0 = (__bf16)xr.x, h1 = (__bf16)xr.y, h2 = (__bf16)xr.z,     \
             h3 = (__bf16)xr.w;                                           \
      bf16x4 hv = {h0, h1, h2, h3};                                       \
      bf16x4 lv = {(__bf16)(xr.x - (float)h0), (__bf16)(xr.y - (float)h1),\
                   (__bf16)(xr.z - (float)h2), (__bf16)(xr.w - (float)h3)};\
      *(bf16x4*)&Xs[xm * XSTR + xk] = hv;                                 \
      *(bf16x4*)&Xs[xm * XSTR + 32 + xk] = lv;                            \
    }                                                                     \
    if ((KS) < 63) {                                                      \
      const int ko = ((KS) + 1) << 5;                                     \
      xr = *(const float4*)(xgp + ko);                                    \
      _Pragma("unroll") for (int nt = 0; nt < 3; ++nt) {                  \
        NH[nt] = *(const bf16x8*)(wph[nt] + ko);                          \
        NL[nt] = *(const bf16x8*)(wpl[nt] + ko);                          \
      }                                                                   \
    }                                                                     \
    __syncthreads();                                                      \
    bf16x8 ah[2], al[2];                                                  \
    _Pragma("unroll") for (int mg = 0; mg < 2; ++mg) {                    \
      ah[mg] = *(bf16x8*)&Xs[(wr * 32 + mg * 16 + l15) * XSTR + q8];      \
      al[mg] = *(bf16x8*)&Xs[(wr * 32 + mg * 16 + l15) * XSTR + 32 + q8]; \
    }                                                                     \
    _Pragma("unroll") for (int nt = 0; nt < 3; ++nt) {                    \
      _Pragma("unroll") for (int mg = 0; mg < 2; ++mg) {                  \
        acc[mg][nt] = MFMA(ah[mg], CH[nt], acc[mg][nt]);                  \
        acc[mg][nt] = MFMA(al[mg], CH[nt], acc[mg][nt]);                  \
        acc[mg][nt] = MFMA(ah[mg], CL[nt], acc[mg][nt]);                  \
      }                                                                   \
    }                                                                     \
  }

__global__ __launch_bounds__(512, 4) void proj_kernel(
    const float* __restrict__ X, const __bf16* __restrict__ wt_hi,
    const __bf16* __restrict__ wt_lo, __bf16* __restrict__ qh,
    __bf16* __restrict__ ql, __bf16* __restrict__ kh,
    __bf16* __restrict__ kl, __bf16* __restrict__ vt) {
  __shared__ __align__(16) __bf16 Xs[64 * XSTR];  // 9216 B total
  const int t = threadIdx.x;
  const int wv = t >> 6, lane = t & 63;
  const int l15 = lane & 15, quad = lane >> 4, q8 = quad * 8;
  const int bi = blockIdx.x;
  const int m0 = (bi >> 1) * 64;
  const int nbase = (bi & 1) * 192;
  const int wr = wv >> 2, wc = wv & 3;  // wave tile: 32m x 48n
  // X staging map: 64 rows x 8 col-quads (one float4/thread)
  const int xm = t >> 3, xk = (t & 7) << 2;
  const float* xgp = X + (size_t)(m0 + xm) * D_ + xk;
  // W fragment base pointers (per nt): row n = nbase + wc*48 + nt*16 + l15
  const __bf16* wph[3];
  const __bf16* wpl[3];
#pragma unroll
  for (int nt = 0; nt < 3; ++nt) {
    size_t ro = (size_t)(nbase + wc * 48 + nt * 16 + l15) * D_ + q8;
    wph[nt] = wt_hi + ro;
    wpl[nt] = wt_lo + ro;
  }
  f32x4 acc[2][3] = {};
  // prefetch kstep 0: X float4 + 6 W fragments
  float4 xr = *(const float4*)xgp;
  bf16x8 wha[3], wla[3], whb[3], wlb[3];
#pragma unroll
  for (int nt = 0; nt < 3; ++nt) {
    wha[nt] = *(const bf16x8*)(wph[nt]);
    wla[nt] = *(const bf16x8*)(wpl[nt]);
  }
  for (int ks2 = 0; ks2 < 64; ks2 += 2) {
    PROJ_STEP(ks2, wha, wla, whb, wlb);
    PROJ_STEP(ks2 + 1, whb, wlb, wha, wla);
  }
  // epilogue (C/D: col = l15 -> n, row = quad*4+reg -> m)
#pragma unroll
  for (int nt = 0; nt < 3; ++nt) {
    int ncb = nbase + wc * 48 + nt * 16;  // 16-aligned, within one z
    int z = ncb >> 7;
    int h = (ncb & 127) + l15;
#pragma unroll
    for (int mg = 0; mg < 2; ++mg) {
      int r0 = m0 + wr * 32 + mg * 16 + quad * 4;
      if (z == 2) {
        int b = m0 >> 11;
        int tt0 = (m0 & 2047) + wr * 32 + mg * 16 + quad * 4;
        bf16x4 pv = {(__bf16)acc[mg][nt][0], (__bf16)acc[mg][nt][1],
                     (__bf16)acc[mg][nt][2], (__bf16)acc[mg][nt][3]};
        *(bf16x4*)&vt[(size_t)(b * H_ + h) * T_ + tt0] = pv;
      } else {
        __bf16* dh = z == 0 ? qh : kh;
        __bf16* dl = z == 0 ? ql : kl;
#pragma unroll
        for (int reg = 0; reg < 4; ++reg) {
          float v = acc[mg][nt][reg];
          __bf16 hi = (__bf16)v;
          dh[(size_t)(r0 + reg) * H_ + h] = hi;
          dl[(size_t)(r0 + reg) * H_ + h] = (__bf16)(v - (float)hi);
        }
      }
    }
  }
}

// ---------------- attention: flash, split-bf16 QK (3-pass), bf16 PV --------
// round-0 structure (two complementary q-halves per block: st=0 -> pi,
// st=1 -> 63-pi, 4 waves each -- balance is INTRA-block, scheduler-proof).
// block mapping b=j&7, pi=j>>3 gives batch<->XCD affinity
// (verified round 1: FETCH 51MB -> 10.6MB). One batch's K/V/Q (~3.5MB)
// fits the XCD's 4MB L2, cutting K/V load latency in the serial chain.
__global__ __launch_bounds__(512, 2) void attn_kernel(
    const __bf16* __restrict__ qh, const __bf16* __restrict__ qlo,
    const __bf16* __restrict__ kh, const __bf16* __restrict__ klo,
    const __bf16* __restrict__ vt, float* __restrict__ out) {
  const int t = threadIdx.x;
  const int wv = t >> 6, st = wv >> 2, cw = wv & 3;
  const int lane = t & 63, l15 = lane & 15, quad = lane >> 4;
  const int j = blockIdx.x, b = j & 7, pi = j >> 3;
  const int qlidx = (st == 0) ? pi : 63 - pi;
  const int t0 = qlidx * 32;
  const int nkt = (qlidx >> 1) + 1;
  __shared__ __align__(16) __bf16 Pbuf[8][32 * 72];
  __shared__ __align__(16) float Obuf[2][32 * 132];
  __shared__ float mlb[2][4][32], llb[2][4][32];
  const size_t qrow0 = (size_t)b * T_ + t0;
  bf16x8 qfh[2][4], qfl[2][4];
#pragma unroll
  for (int mg = 0; mg < 2; ++mg)
#pragma unroll
    for (int ds = 0; ds < 4; ++ds) {
      size_t off = (qrow0 + mg * 16 + l15) * H_ + ds * 32 + quad * 8;
      qfh[mg][ds] = *(const bf16x8*)(qh + off);
      qfl[mg][ds] = *(const bf16x8*)(qlo + off);
    }
  f32x4 O[2][8] = {};
  float ms[2][4], ls[2][4];
#pragma unroll
  for (int mg = 0; mg < 2; ++mg)
#pragma unroll
    for (int reg = 0; reg < 4; ++reg) {
      ms[mg][reg] = -INFINITY;
      ls[mg][reg] = 0.f;
    }
  const __bf16* vtb = vt + (size_t)b * H_ * T_;
  const float scale = 11.313708498984761f;  // sqrt(128); ref multiplies
  for (int kt_i = cw; kt_i < nkt; kt_i += 4) {
    const int kt = kt_i * 64;
    f32x4 S[2][4] = {};
#pragma unroll
    for (int ds = 0; ds < 4; ++ds)
#pragma unroll
      for (int ct = 0; ct < 4; ++ct) {
        size_t koff =
            ((size_t)b * T_ + kt + ct * 16 + l15) * H_ + ds * 32 + quad * 8;
        bf16x8 bh = *(const bf16x8*)(kh + koff);
        bf16x8 bl = *(const bf16x8*)(klo + koff);
#pragma unroll
        for (int mg = 0; mg < 2; ++mg) {
          S[mg][ct] = MFMA(qfh[mg][ds], bh, S[mg][ct]);
          S[mg][ct] = MFMA(qfl[mg][ds], bh, S[mg][ct]);
          S[mg][ct] = MFMA(qfh[mg][ds], bl, S[mg][ct]);
        }
      }
    const bool diag = (kt_i == nkt - 1);
#pragma unroll
    for (int mg = 0; mg < 2; ++mg)
#pragma unroll
      for (int ct = 0; ct < 4; ++ct)
#pragma unroll
        for (int reg = 0; reg < 4; ++reg) {
          float s = S[mg][ct][reg] * scale;
          if (diag && (kt + ct * 16 + l15 > t0 + mg * 16 + quad * 4 + reg))
            s = -1e30f;
          S[mg][ct][reg] = s;
        }
    float al_[2][4];
#pragma unroll
    for (int mg = 0; mg < 2; ++mg)
#pragma unroll
      for (int reg = 0; reg < 4; ++reg) {
        float r = fmaxf(fmaxf(S[mg][0][reg], S[mg][1][reg]),
                        fmaxf(S[mg][2][reg], S[mg][3][reg]));
        r = fmaxf(r, __shfl_xor(r, 1));
        r = fmaxf(r, __shfl_xor(r, 2));
        r = fmaxf(r, __shfl_xor(r, 4));
        r = fmaxf(r, __shfl_xor(r, 8));
        float mn = fmaxf(ms[mg][reg], r);
        float a = __expf(ms[mg][reg] - mn);
        ms[mg][reg] = mn;
        float ps = 0.f;
#pragma unroll
        for (int ct = 0; ct < 4; ++ct) {
          float p = __expf(S[mg][ct][reg] - mn);
          S[mg][ct][reg] = p;
          ps += p;
        }
        ps += __shfl_xor(ps, 1);
        ps += __shfl_xor(ps, 2);
        ps += __shfl_xor(ps, 4);
        ps += __shfl_xor(ps, 8);
        ls[mg][reg] = ls[mg][reg] * a + ps;
        al_[mg][reg] = a;
      }
#pragma unroll
    for (int mg = 0; mg < 2; ++mg)
#pragma unroll
      for (int ht = 0; ht < 8; ++ht)
#pragma unroll
        for (int reg = 0; reg < 4; ++reg) O[mg][ht][reg] *= al_[mg][reg];
#pragma unroll
    for (int mg = 0; mg < 2; ++mg)
#pragma unroll
      for (int ct = 0; ct < 4; ++ct)
#pragma unroll
        for (int reg = 0; reg < 4; ++reg)
          Pbuf[wv][(mg * 16 + quad * 4 + reg) * 72 + ct * 16 + l15] =
              (__bf16)S[mg][ct][reg];
#pragma unroll
    for (int ks = 0; ks < 2; ++ks) {
      bf16x8 pf0 = *(bf16x8*)&Pbuf[wv][(l15)*72 + ks * 32 + quad * 8];
      bf16x8 pf1 = *(bf16x8*)&Pbuf[wv][(16 + l15) * 72 + ks * 32 + quad * 8];
#pragma unroll
      for (int ht = 0; ht < 8; ++ht) {
        bf16x8 vf = *(const bf16x8*)&vtb[(size_t)(ht * 16 + l15) * T_ + kt +
                                         ks * 32 + quad * 8];
        O[0][ht] = MFMA(pf0, vf, O[0][ht]);
        O[1][ht] = MFMA(pf1, vf, O[1][ht]);
      }
    }
  }
  if (l15 == 0) {
#pragma unroll
    for (int mg = 0; mg < 2; ++mg)
#pragma unroll
      for (int reg = 0; reg < 4; ++reg) {
        mlb[st][cw][mg * 16 + quad * 4 + reg] = ms[mg][reg];
        llb[st][cw][mg * 16 + quad * 4 + reg] = ls[mg][reg];
      }
  }
  for (int i = t; i < 2 * 32 * 132; i += 512) ((float*)Obuf)[i] = 0.f;
  __syncthreads();
  float aw[2][4];
#pragma unroll
  for (int mg = 0; mg < 2; ++mg)
#pragma unroll
    for (int reg = 0; reg < 4; ++reg) {
      int row = mg * 16 + quad * 4 + reg;
      float M = fmaxf(fmaxf(mlb[st][0][row], mlb[st][1][row]),
                      fmaxf(mlb[st][2][row], mlb[st][3][row]));
      float L = 0.f;
#pragma unroll
      for (int w = 0; w < 4; ++w)
        L += llb[st][w][row] * __expf(mlb[st][w][row] - M);
      aw[mg][reg] = __expf(ms[mg][reg] - M) / L;
    }
#pragma unroll
  for (int mg = 0; mg < 2; ++mg)
#pragma unroll
    for (int ht = 0; ht < 8; ++ht)
#pragma unroll
      for (int reg = 0; reg < 4; ++reg)
        atomicAdd(&Obuf[st][(mg * 16 + quad * 4 + reg) * 132 + ht * 16 + l15],
                  O[mg][ht][reg] * aw[mg][reg]);
  __syncthreads();
  {
    const int stw = t >> 8, tt = t & 255;
    const int qlw = (stw == 0) ? pi : 63 - pi;
    const size_t obase = ((size_t)b * T_ + qlw * 32) * H_;
#pragma unroll
    for (int i = 0; i < 4; ++i) {
      int f4 = i * 256 + tt;
      int row = f4 >> 5, c = (f4 & 31) << 2;
      *(float4*)&out[obase + (size_t)row * H_ + c] =
          *(float4*)&Obuf[stw][row * 132 + c];
    }
  }
}

extern "C" void kernel_launch(void* const* d_in, const int* in_sizes, int n_in,
                              void* d_out, int out_size, void* d_ws, size_t ws_size,
                              hipStream_t stream) {
  const float* x = (const float*)d_in[0];
  const float* Wq = (const float*)d_in[1];
  const float* Wk = (const float*)d_in[2];
  const float* Wv = (const float*)d_in[3];
  __bf16* ws = (__bf16*)d_ws;
  float* out = (float*)d_out;
  prep_kernel<<<dim3(32, 3), 256, 0, stream>>>(Wq, Wk, Wv, ws + WTH_OFF,
                                               ws + WTL_OFF);
  proj_kernel<<<512, 512, 0, stream>>>(x, ws + WTH_OFF, ws + WTL_OFF,
                                       ws + QH_OFF, ws + QL_OFF, ws + KH_OFF,
                                       ws + KL_OFF, ws + VT_OFF);
  attn_kernel<<<256, 512, 0, stream>>>(ws + QH_OFF, ws + QL_OFF, ws + KH_OFF,
                                       ws + KL_OFF, ws + VT_OFF, out);
}

// Round 7
// 397.811 us; speedup vs baseline: 1.2294x; 1.2294x over previous
//
#include <hip/hip_runtime.h>
#include <math.h>

#define B_ 8
#define T_ 2048
#define D_ 2048
#define H_ 128
#define M_ (B_ * T_)

typedef __bf16 bf16x8 __attribute__((ext_vector_type(8)));
typedef __bf16 bf16x4 __attribute__((ext_vector_type(4)));
typedef float f32x4 __attribute__((ext_vector_type(4)));

#define MFMA(a, b, c) __builtin_amdgcn_mfma_f32_16x16x32_bf16(a, b, c, 0, 0, 0)

// ws layout (bf16 elements)
#define QH_OFF 0
#define QL_OFF (1 * 2097152)  // M_*H_
#define KH_OFF (2 * 2097152)
#define KL_OFF (3 * 2097152)
#define VT_OFF (4 * 2097152)        // vt[b][h][t]
#define WTH_OFF (5 * 2097152)       // wpk_hi[g][ks][lane][8] fragment-packed
#define WTL_OFF (WTH_OFF + 786432)  // 3*128*2048

// ---------------- prep: W[k][n] fp32 -> fragment-packed hi/lo bf16 ---------
// Packed layout: for n-group g = n_full>>4 (24 groups of 16 rows) and kstep
// s (k = 32s..32s+31), the 64-lane B-fragment lives contiguously at
// elem ((g*64 + s)*64 + lane)*8, lane = quad*16 + l15, holding
// wt[n=16g+l15][k=32s+8*quad+j].  A wave's B-frag load is ONE coalesced
// 1KB global_load_dwordx4 (round-6 lesson: row-scattered 64B segments
// stall VMEM; fragment-packing restores ideal lane-contiguous pattern).
__global__ __launch_bounds__(256) void prep_kernel(
    const float* __restrict__ Wq, const float* __restrict__ Wk,
    const float* __restrict__ Wv, __bf16* __restrict__ wpk_hi,
    __bf16* __restrict__ wpk_lo) {
  const int z = blockIdx.y;
  const int k0 = blockIdx.x * 64;
  const float* W = z == 0 ? Wq : z == 1 ? Wk : Wv;
  __shared__ float tile[64][132];
  const int t = threadIdx.x;
#pragma unroll
  for (int it = 0; it < 8; ++it) {
    int f4 = it * 256 + t;  // 2048 float4 = 64 rows x 32
    int row = f4 >> 5, c = (f4 & 31) << 2;
    *(float4*)&tile[row][c] = *(const float4*)&W[(size_t)(k0 + row) * H_ + c];
  }
  __syncthreads();
  int n = t >> 1, kh = (t & 1) << 5;  // row n (0..127), k-base k0+kh
  __bf16 h[32], l[32];
#pragma unroll
  for (int kk = 0; kk < 32; ++kk) {
    float x = tile[kh + kk][n];
    __bf16 hi = (__bf16)x;
    h[kk] = hi;
    l[kk] = (__bf16)(x - (float)hi);
  }
  const int nf = z * H_ + n;           // 0..383
  const int g = nf >> 4, l15 = nf & 15;
  const int s = (k0 + kh) >> 5;        // constant across the 4 chunks
#pragma unroll
  for (int c = 0; c < 4; ++c) {        // chunk c -> quad c
    size_t dst = ((size_t)(g * 64 + s) * 64 + c * 16 + l15) * 8;
    *(bf16x8*)&wpk_hi[dst] = *(bf16x8*)&h[c * 8];
    *(bf16x8*)&wpk_lo[dst] = *(bf16x8*)&l[c * 8];
  }
}

// ---------------- proj: X-in-LDS, W fragment-packed from L2 ---------------
// v5: 512 blocks x 512 thr (8 waves). Block = 64m x 192n (n-half = bi&1,
// parity->XCD so the 1.5MB packed W-half is L2-resident). Wave = 32m x 48n.
// Round-5 PMC: DS pipe was the pole (14KB/wave-kstep vs 90cyc MFMA).
// Round-6: W-direct from wt[n][k] regressed (row-scattered VMEM). Here W
// comes from the PACKED layout: 6 coalesced 1KB loads/kstep/wave, reg-
// double-buffered one kstep ahead; LDS holds only X (9.2KB). DS traffic
// drops to ~5KB/wave-kstep (4 b128 A-reads + 2 b64 X-writes).
// Numerics bit-identical (same fragment values, same MFMA order).
#define XSTR 72  // X row-pair stride (32 hi | 32 lo | 8 pad) = 144 B

#define PROJ_STEP(KS, CH, CL, NH, NL)                                      \
  {                                                                        \
    __syncthreads();                                                       \
    {                                                                      \
      __bf16 h0 = (__bf16)xr.x, h1 = (__bf16)xr.y, h2 = (__bf16)xr.z,      \
             h3 = (__bf16)xr.w;                                            \
      bf16x4 hv = {h0, h1, h2, h3};                                        \
      bf16x4 lv = {(__bf16)(xr.x - (float)h0), (__bf16)(xr.y - (float)h1), \
                   (__bf16)(xr.z - (float)h2), (__bf16)(xr.w - (float)h3)};\
      *(bf16x4*)&Xs[xm * XSTR + xk] = hv;                                  \
      *(bf16x4*)&Xs[xm * XSTR + 32 + xk] = lv;                             \
    }                                                                      \
    if ((KS) < 63) {                                                       \
      const int ko = ((KS) + 1) << 5;                                      \
      xr = *(const float4*)(xgp + ko);                                     \
      _Pragma("unroll") for (int nt = 0; nt < 3; ++nt) {                   \
        NH[nt] = *(const bf16x8*)(wph[nt] + ((KS) + 1) * 512);             \
        NL[nt] = *(const bf16x8*)(wpl[nt] + ((KS) + 1) * 512);             \
      }                                                                    \
    }                                                                      \
    __syncthreads();                                                       \
    bf16x8 ah[2], al[2];                                                   \
    _Pragma("unroll") for (int mg = 0; mg < 2; ++mg) {                     \
      ah[mg] = *(bf16x8*)&Xs[(wr * 32 + mg * 16 + l15) * XSTR + q8];       \
      al[mg] = *(bf16x8*)&Xs[(wr * 32 + mg * 16 + l15) * XSTR + 32 + q8];  \
    }                                                                      \
    _Pragma("unroll") for (int nt = 0; nt < 3; ++nt) {                     \
      _Pragma("unroll") for (int mg = 0; mg < 2; ++mg) {                   \
        acc[mg][nt] = MFMA(ah[mg], CH[nt], acc[mg][nt]);                   \
        acc[mg][nt] = MFMA(al[mg], CH[nt], acc[mg][nt]);                   \
        acc[mg][nt] = MFMA(ah[mg], CL[nt], acc[mg][nt]);                   \
      }                                                                    \
    }                                                                      \
  }

__global__ __launch_bounds__(512, 4) void proj_kernel(
    const float* __restrict__ X, const __bf16* __restrict__ wpk_hi,
    const __bf16* __restrict__ wpk_lo, __bf16* __restrict__ qh,
    __bf16* __restrict__ ql, __bf16* __restrict__ kh,
    __bf16* __restrict__ kl, __bf16* __restrict__ vt) {
  __shared__ __align__(16) __bf16 Xs[64 * XSTR];  // 9216 B total
  const int t = threadIdx.x;
  const int wv = t >> 6, lane = t & 63;
  const int l15 = lane & 15, quad = lane >> 4, q8 = quad * 8;
  const int bi = blockIdx.x;
  const int m0 = (bi >> 1) * 64;
  const int nbase = (bi & 1) * 192;
  const int wr = wv >> 2, wc = wv & 3;  // wave tile: 32m x 48n
  // X staging map: 64 rows x 8 col-quads (one float4/thread)
  const int xm = t >> 3, xk = (t & 7) << 2;
  const float* xgp = X + (size_t)(m0 + xm) * D_ + xk;
  // W packed fragment bases (per nt): group g, lane-contiguous
  const __bf16* wph[3];
  const __bf16* wpl[3];
#pragma unroll
  for (int nt = 0; nt < 3; ++nt) {
    int g = (nbase >> 4) + wc * 3 + nt;
    size_t off = (size_t)g * 32768 + (size_t)lane * 8;  // g*64*64*8
    wph[nt] = wpk_hi + off;
    wpl[nt] = wpk_lo + off;
  }
  f32x4 acc[2][3] = {};
  // prefetch kstep 0: X float4 + 6 W fragments
  float4 xr = *(const float4*)xgp;
  bf16x8 wha[3], wla[3], whb[3], wlb[3];
#pragma unroll
  for (int nt = 0; nt < 3; ++nt) {
    wha[nt] = *(const bf16x8*)(wph[nt]);
    wla[nt] = *(const bf16x8*)(wpl[nt]);
  }
  for (int ks2 = 0; ks2 < 64; ks2 += 2) {
    PROJ_STEP(ks2, wha, wla, whb, wlb);
    PROJ_STEP(ks2 + 1, whb, wlb, wha, wla);
  }
  // epilogue (C/D: col = l15 -> n, row = quad*4+reg -> m)
#pragma unroll
  for (int nt = 0; nt < 3; ++nt) {
    int ncb = nbase + wc * 48 + nt * 16;  // 16-aligned, within one z
    int z = ncb >> 7;
    int h = (ncb & 127) + l15;
#pragma unroll
    for (int mg = 0; mg < 2; ++mg) {
      int r0 = m0 + wr * 32 + mg * 16 + quad * 4;
      if (z == 2) {
        int b = m0 >> 11;
        int tt0 = (m0 & 2047) + wr * 32 + mg * 16 + quad * 4;
        bf16x4 pv = {(__bf16)acc[mg][nt][0], (__bf16)acc[mg][nt][1],
                     (__bf16)acc[mg][nt][2], (__bf16)acc[mg][nt][3]};
        *(bf16x4*)&vt[(size_t)(b * H_ + h) * T_ + tt0] = pv;
      } else {
        __bf16* dh = z == 0 ? qh : kh;
        __bf16* dl = z == 0 ? ql : kl;
#pragma unroll
        for (int reg = 0; reg < 4; ++reg) {
          float v = acc[mg][nt][reg];
          __bf16 hi = (__bf16)v;
          dh[(size_t)(r0 + reg) * H_ + h] = hi;
          dl[(size_t)(r0 + reg) * H_ + h] = (__bf16)(v - (float)hi);
        }
      }
    }
  }
}

// ---------------- attention: flash, split-bf16 QK (3-pass), bf16 PV --------
// round-0 structure (two complementary q-halves per block: st=0 -> pi,
// st=1 -> 63-pi, 4 waves each -- balance is INTRA-block, scheduler-proof).
// block mapping b=j&7, pi=j>>3 gives batch<->XCD affinity
// (verified round 1: FETCH 51MB -> 10.6MB). One batch's K/V/Q (~3.5MB)
// fits the XCD's 4MB L2, cutting K/V load latency in the serial chain.
__global__ __launch_bounds__(512, 2) void attn_kernel(
    const __bf16* __restrict__ qh, const __bf16* __restrict__ qlo,
    const __bf16* __restrict__ kh, const __bf16* __restrict__ klo,
    const __bf16* __restrict__ vt, float* __restrict__ out) {
  const int t = threadIdx.x;
  const int wv = t >> 6, st = wv >> 2, cw = wv & 3;
  const int lane = t & 63, l15 = lane & 15, quad = lane >> 4;
  const int j = blockIdx.x, b = j & 7, pi = j >> 3;
  const int qlidx = (st == 0) ? pi : 63 - pi;
  const int t0 = qlidx * 32;
  const int nkt = (qlidx >> 1) + 1;
  __shared__ __align__(16) __bf16 Pbuf[8][32 * 72];
  __shared__ __align__(16) float Obuf[2][32 * 132];
  __shared__ float mlb[2][4][32], llb[2][4][32];
  const size_t qrow0 = (size_t)b * T_ + t0;
  bf16x8 qfh[2][4], qfl[2][4];
#pragma unroll
  for (int mg = 0; mg < 2; ++mg)
#pragma unroll
    for (int ds = 0; ds < 4; ++ds) {
      size_t off = (qrow0 + mg * 16 + l15) * H_ + ds * 32 + quad * 8;
      qfh[mg][ds] = *(const bf16x8*)(qh + off);
      qfl[mg][ds] = *(const bf16x8*)(qlo + off);
    }
  f32x4 O[2][8] = {};
  float ms[2][4], ls[2][4];
#pragma unroll
  for (int mg = 0; mg < 2; ++mg)
#pragma unroll
    for (int reg = 0; reg < 4; ++reg) {
      ms[mg][reg] = -INFINITY;
      ls[mg][reg] = 0.f;
    }
  const __bf16* vtb = vt + (size_t)b * H_ * T_;
  const float scale = 11.313708498984761f;  // sqrt(128); ref multiplies
  for (int kt_i = cw; kt_i < nkt; kt_i += 4) {
    const int kt = kt_i * 64;
    f32x4 S[2][4] = {};
#pragma unroll
    for (int ds = 0; ds < 4; ++ds)
#pragma unroll
      for (int ct = 0; ct < 4; ++ct) {
        size_t koff =
            ((size_t)b * T_ + kt + ct * 16 + l15) * H_ + ds * 32 + quad * 8;
        bf16x8 bh = *(const bf16x8*)(kh + koff);
        bf16x8 bl = *(const bf16x8*)(klo + koff);
#pragma unroll
        for (int mg = 0; mg < 2; ++mg) {
          S[mg][ct] = MFMA(qfh[mg][ds], bh, S[mg][ct]);
          S[mg][ct] = MFMA(qfl[mg][ds], bh, S[mg][ct]);
          S[mg][ct] = MFMA(qfh[mg][ds], bl, S[mg][ct]);
        }
      }
    const bool diag = (kt_i == nkt - 1);
#pragma unroll
    for (int mg = 0; mg < 2; ++mg)
#pragma unroll
      for (int ct = 0; ct < 4; ++ct)
#pragma unroll
        for (int reg = 0; reg < 4; ++reg) {
          float s = S[mg][ct][reg] * scale;
          if (diag && (kt + ct * 16 + l15 > t0 + mg * 16 + quad * 4 + reg))
            s = -1e30f;
          S[mg][ct][reg] = s;
        }
    float al_[2][4];
#pragma unroll
    for (int mg = 0; mg < 2; ++mg)
#pragma unroll
      for (int reg = 0; reg < 4; ++reg) {
        float r = fmaxf(fmaxf(S[mg][0][reg], S[mg][1][reg]),
                        fmaxf(S[mg][2][reg], S[mg][3][reg]));
        r = fmaxf(r, __shfl_xor(r, 1));
        r = fmaxf(r, __shfl_xor(r, 2));
        r = fmaxf(r, __shfl_xor(r, 4));
        r = fmaxf(r, __shfl_xor(r, 8));
        float mn = fmaxf(ms[mg][reg], r);
        float a = __expf(ms[mg][reg] - mn);
        ms[mg][reg] = mn;
        float ps = 0.f;
#pragma unroll
        for (int ct = 0; ct < 4; ++ct) {
          float p = __expf(S[mg][ct][reg] - mn);
          S[mg][ct][reg] = p;
          ps += p;
        }
        ps += __shfl_xor(ps, 1);
        ps += __shfl_xor(ps, 2);
        ps += __shfl_xor(ps, 4);
        ps += __shfl_xor(ps, 8);
        ls[mg][reg] = ls[mg][reg] * a + ps;
        al_[mg][reg] = a;
      }
#pragma unroll
    for (int mg = 0; mg < 2; ++mg)
#pragma unroll
      for (int ht = 0; ht < 8; ++ht)
#pragma unroll
        for (int reg = 0; reg < 4; ++reg) O[mg][ht][reg] *= al_[mg][reg];
#pragma unroll
    for (int mg = 0; mg < 2; ++mg)
#pragma unroll
      for (int ct = 0; ct < 4; ++ct)
#pragma unroll
        for (int reg = 0; reg < 4; ++reg)
          Pbuf[wv][(mg * 16 + quad * 4 + reg) * 72 + ct * 16 + l15] =
              (__bf16)S[mg][ct][reg];
#pragma unroll
    for (int ks = 0; ks < 2; ++ks) {
      bf16x8 pf0 = *(bf16x8*)&Pbuf[wv][(l15)*72 + ks * 32 + quad * 8];
      bf16x8 pf1 = *(bf16x8*)&Pbuf[wv][(16 + l15) * 72 + ks * 32 + quad * 8];
#pragma unroll
      for (int ht = 0; ht < 8; ++ht) {
        bf16x8 vf = *(const bf16x8*)&vtb[(size_t)(ht * 16 + l15) * T_ + kt +
                                         ks * 32 + quad * 8];
        O[0][ht] = MFMA(pf0, vf, O[0][ht]);
        O[1][ht] = MFMA(pf1, vf, O[1][ht]);
      }
    }
  }
  if (l15 == 0) {
#pragma unroll
    for (int mg = 0; mg < 2; ++mg)
#pragma unroll
      for (int reg = 0; reg < 4; ++reg) {
        mlb[st][cw][mg * 16 + quad * 4 + reg] = ms[mg][reg];
        llb[st][cw][mg * 16 + quad * 4 + reg] = ls[mg][reg];
      }
  }
  for (int i = t; i < 2 * 32 * 132; i += 512) ((float*)Obuf)[i] = 0.f;
  __syncthreads();
  float aw[2][4];
#pragma unroll
  for (int mg = 0; mg < 2; ++mg)
#pragma unroll
    for (int reg = 0; reg < 4; ++reg) {
      int row = mg * 16 + quad * 4 + reg;
      float M = fmaxf(fmaxf(mlb[st][0][row], mlb[st][1][row]),
                      fmaxf(mlb[st][2][row], mlb[st][3][row]));
      float L = 0.f;
#pragma unroll
      for (int w = 0; w < 4; ++w)
        L += llb[st][w][row] * __expf(mlb[st][w][row] - M);
      aw[mg][reg] = __expf(ms[mg][reg] - M) / L;
    }
#pragma unroll
  for (int mg = 0; mg < 2; ++mg)
#pragma unroll
    for (int ht = 0; ht < 8; ++ht)
#pragma unroll
      for (int reg = 0; reg < 4; ++reg)
        atomicAdd(&Obuf[st][(mg * 16 + quad * 4 + reg) * 132 + ht * 16 + l15],
                  O[mg][ht][reg] * aw[mg][reg]);
  __syncthreads();
  {
    const int stw = t >> 8, tt = t & 255;
    const int qlw = (stw == 0) ? pi : 63 - pi;
    const size_t obase = ((size_t)b * T_ + qlw * 32) * H_;
#pragma unroll
    for (int i = 0; i < 4; ++i) {
      int f4 = i * 256 + tt;
      int row = f4 >> 5, c = (f4 & 31) << 2;
      *(float4*)&out[obase + (size_t)row * H_ + c] =
          *(float4*)&Obuf[stw][row * 132 + c];
    }
  }
}

extern "C" void kernel_launch(void* const* d_in, const int* in_sizes, int n_in,
                              void* d_out, int out_size, void* d_ws, size_t ws_size,
                              hipStream_t stream) {
  const float* x = (const float*)d_in[0];
  const float* Wq = (const float*)d_in[1];
  const float* Wk = (const float*)d_in[2];
  const float* Wv = (const float*)d_in[3];
  __bf16* ws = (__bf16*)d_ws;
  float* out = (float*)d_out;
  prep_kernel<<<dim3(32, 3), 256, 0, stream>>>(Wq, Wk, Wv, ws + WTH_OFF,
                                               ws + WTL_OFF);
  proj_kernel<<<512, 512, 0, stream>>>(x, ws + WTH_OFF, ws + WTL_OFF,
                                       ws + QH_OFF, ws + QL_OFF, ws + KH_OFF,
                                       ws + KL_OFF, ws + VT_OFF);
  attn_kernel<<<256, 512, 0, stream>>>(ws + QH_OFF, ws + QL_OFF, ws + KH_OFF,
                                       ws + KL_OFF, ws + VT_OFF, out);
}

// Round 8
// 384.902 us; speedup vs baseline: 1.2706x; 1.0335x over previous
//
#include <hip/hip_runtime.h>
#include <math.h>

#define B_ 8
#define T_ 2048
#define D_ 2048
#define H_ 128
#define M_ (B_ * T_)

typedef __bf16 bf16x8 __attribute__((ext_vector_type(8)));
typedef __bf16 bf16x4 __attribute__((ext_vector_type(4)));
typedef float f32x4 __attribute__((ext_vector_type(4)));

#define MFMA(a, b, c) __builtin_amdgcn_mfma_f32_16x16x32_bf16(a, b, c, 0, 0, 0)

// ws layout (bf16 elements)
#define QH_OFF 0
#define QL_OFF (1 * 2097152)  // M_*H_
#define KH_OFF (2 * 2097152)
#define KL_OFF (3 * 2097152)
#define VT_OFF (4 * 2097152)        // vt[b][h][t]
#define WTH_OFF (5 * 2097152)       // wt_hi[z*128+n][k]
#define WTL_OFF (WTH_OFF + 786432)  // 3*128*2048

// ---------------- prep: W[k][n] fp32 -> Wt_hi/lo[n][k] bf16 ----------------
__global__ __launch_bounds__(256) void prep_kernel(
    const float* __restrict__ Wq, const float* __restrict__ Wk,
    const float* __restrict__ Wv, __bf16* __restrict__ wt_hi,
    __bf16* __restrict__ wt_lo) {
  const int z = blockIdx.y;
  const int k0 = blockIdx.x * 64;
  const float* W = z == 0 ? Wq : z == 1 ? Wk : Wv;
  __shared__ float tile[64][132];
  const int t = threadIdx.x;
#pragma unroll
  for (int it = 0; it < 8; ++it) {
    int f4 = it * 256 + t;  // 2048 float4 = 64 rows x 32
    int row = f4 >> 5, c = (f4 & 31) << 2;
    *(float4*)&tile[row][c] = *(const float4*)&W[(size_t)(k0 + row) * H_ + c];
  }
  __syncthreads();
  int n = t >> 1, kh = (t & 1) << 5;
  __bf16 h[32], l[32];
#pragma unroll
  for (int kk = 0; kk < 32; ++kk) {
    float x = tile[kh + kk][n];
    __bf16 hi = (__bf16)x;
    h[kk] = hi;
    l[kk] = (__bf16)(x - (float)hi);
  }
  size_t base = (size_t)(z * H_ + n) * D_ + k0 + kh;
#pragma unroll
  for (int c = 0; c < 4; ++c) {
    *(bf16x8*)&wt_hi[base + c * 8] = *(bf16x8*)&h[c * 8];
    *(bf16x8*)&wt_lo[base + c * 8] = *(bf16x8*)&l[c * 8];
  }
}

// ---------------- proj: block-shared-LDS split-bf16 MFMA -------------------
// v6 = round-5 structure (verified 132us: 512 blocks x 512 thr, 8 waves,
// block = 64m x 192n, n-half = bi&1 -> XCD parity, W+X staged via LDS,
// 2 barriers/kstep) + ONE change: 2-kstep-deep register prefetch.
// Rounds 5-7 evidence: DS traffic and occupancy are NOT the pole; the
// invariant cost is the vmcnt drain before each barrier -- X is a 268MB
// HBM stream (~900cyc miss) issued only 1 kstep ahead of its ds_write, so
// every kstep the whole block stalls ~HBM-latency in lockstep. Depth-2
// (sets A/B, statically unrolled per rule #20) gives loads ~2 ksteps of
// slack so the drain finds data already landed. Numerics bit-identical
// to round 5 (same LDS contents per kstep, same MFMA order).
#define WSTR 36  // W row stride in bf16 (72 B): b64 frag reads, conflict-free
#define XSTR 72  // X row-pair stride (32 hi | 32 lo | 8 pad) = 144 B

#define PSTEP(KS, XR, WRG)                                                 \
  {                                                                        \
    __syncthreads(); /* prior kstep's LDS reads complete */                \
    {                                                                      \
      __bf16 h0 = (__bf16)XR.x, h1 = (__bf16)XR.y, h2 = (__bf16)XR.z,      \
             h3 = (__bf16)XR.w;                                            \
      bf16x4 hv = {h0, h1, h2, h3};                                        \
      bf16x4 lv = {(__bf16)(XR.x - (float)h0), (__bf16)(XR.y - (float)h1), \
                   (__bf16)(XR.z - (float)h2), (__bf16)(XR.w - (float)h3)};\
      *(bf16x4*)&Xs[xm * XSTR + xk] = hv;                                  \
      *(bf16x4*)&Xs[xm * XSTR + 32 + xk] = lv;                             \
    }                                                                      \
    _Pragma("unroll") for (int p = 0; p < 3; ++p) {                        \
      bf16x4 a, b;                                                         \
      _Pragma("unroll") for (int jj = 0; jj < 4; ++jj) {                   \
        a[jj] = WRG[p][jj];                                                \
        b[jj] = WRG[p][jj + 4];                                            \
      }                                                                    \
      *(bf16x4*)(wdst[p]) = a;                                             \
      *(bf16x4*)(wdst[p] + 4) = b;                                         \
    }                                                                      \
    if ((KS) < 62) { /* issue loads for kstep KS+2 into this reg set */    \
      const int ko = ((KS) + 2) << 5;                                      \
      XR = *(const float4*)(xgp + ko);                                     \
      _Pragma("unroll") for (int p = 0; p < 3; ++p)                        \
        WRG[p] = *(const bf16x8*)(wsrc[p] + ko);                           \
    }                                                                      \
    __syncthreads(); /* staged tile visible */                             \
    bf16x8 ah[2], al[2];                                                   \
    _Pragma("unroll") for (int mg = 0; mg < 2; ++mg) {                     \
      ah[mg] = *(bf16x8*)&Xs[(wr * 32 + mg * 16 + l15) * XSTR + q8];       \
      al[mg] = *(bf16x8*)&Xs[(wr * 32 + mg * 16 + l15) * XSTR + 32 + q8];  \
    }                                                                      \
    _Pragma("unroll") for (int nt = 0; nt < 3; ++nt) {                     \
      const int n = wc * 48 + nt * 16 + l15;                               \
      bf16x4 b0 = *(bf16x4*)&Wh[n * WSTR + q8];                            \
      bf16x4 b1 = *(bf16x4*)&Wh[n * WSTR + q8 + 4];                        \
      bf16x4 b2 = *(bf16x4*)&Wl[n * WSTR + q8];                            \
      bf16x4 b3 = *(bf16x4*)&Wl[n * WSTR + q8 + 4];                        \
      bf16x8 bh, bl;                                                       \
      _Pragma("unroll") for (int jj = 0; jj < 4; ++jj) {                   \
        bh[jj] = b0[jj];                                                   \
        bh[jj + 4] = b1[jj];                                               \
        bl[jj] = b2[jj];                                                   \
        bl[jj + 4] = b3[jj];                                               \
      }                                                                    \
      _Pragma("unroll") for (int mg = 0; mg < 2; ++mg) {                   \
        acc[mg][nt] = MFMA(ah[mg], bh, acc[mg][nt]);                       \
        acc[mg][nt] = MFMA(al[mg], bh, acc[mg][nt]);                       \
        acc[mg][nt] = MFMA(ah[mg], bl, acc[mg][nt]);                       \
      }                                                                    \
    }                                                                      \
  }

__global__ __launch_bounds__(512, 4) void proj_kernel(
    const float* __restrict__ X, const __bf16* __restrict__ wt_hi,
    const __bf16* __restrict__ wt_lo, __bf16* __restrict__ qh,
    __bf16* __restrict__ ql, __bf16* __restrict__ kh,
    __bf16* __restrict__ kl, __bf16* __restrict__ vt) {
  __shared__ __align__(16) __bf16 Wh[192 * WSTR];  // 13824 B
  __shared__ __align__(16) __bf16 Wl[192 * WSTR];  // 13824 B
  __shared__ __align__(16) __bf16 Xs[64 * XSTR];   //  9216 B  (total 36864)
  const int t = threadIdx.x;
  const int wv = t >> 6, lane = t & 63;
  const int l15 = lane & 15, quad = lane >> 4, q8 = quad * 8;
  const int bi = blockIdx.x;
  const int m0 = (bi >> 1) * 64;
  const int nbase = (bi & 1) * 192;
  const int wr = wv >> 2, wc = wv & 3;  // wave tile: 32m x 48n
  // X staging map: 64 rows x 8 col-quads (one float4/thread)
  const int xm = t >> 3, xk = (t & 7) << 2;
  const float* xgp = X + (size_t)(m0 + xm) * D_ + xk;
  // W staging: 1536 tasks = (hi|lo) x 192 rows x 4 8-elem chunks, 3/thread
  const __bf16* wsrc[3];
  __bf16* wdst[3];
#pragma unroll
  for (int p = 0; p < 3; ++p) {
    int c = t + (p << 9);
    int sel = c >= 768;          // 0 = hi, 1 = lo
    int cr = sel ? c - 768 : c;  // 0..767
    int r = cr >> 2, o = (c & 3) << 3;
    wsrc[p] = (sel ? wt_lo : wt_hi) + (size_t)(nbase + r) * D_ + o;
    wdst[p] = (sel ? Wl : Wh) + r * WSTR + o;
  }
  f32x4 acc[2][3] = {};
  // depth-2 prefetch: set A = even ksteps, set B = odd ksteps
  float4 xrA = *(const float4*)xgp;         // ks 0
  float4 xrB = *(const float4*)(xgp + 32);  // ks 1
  bf16x8 wrA[3], wrB[3];
#pragma unroll
  for (int p = 0; p < 3; ++p) {
    wrA[p] = *(const bf16x8*)(wsrc[p]);       // ks 0
    wrB[p] = *(const bf16x8*)(wsrc[p] + 32);  // ks 1
  }
  for (int ks2 = 0; ks2 < 64; ks2 += 2) {
    PSTEP(ks2, xrA, wrA);
    PSTEP(ks2 + 1, xrB, wrB);
  }
  // epilogue (C/D: col = l15 -> n, row = quad*4+reg -> m)
#pragma unroll
  for (int nt = 0; nt < 3; ++nt) {
    int ncb = nbase + wc * 48 + nt * 16;  // 16-aligned, within one z
    int z = ncb >> 7;
    int h = (ncb & 127) + l15;
#pragma unroll
    for (int mg = 0; mg < 2; ++mg) {
      int r0 = m0 + wr * 32 + mg * 16 + quad * 4;
      if (z == 2) {
        int b = m0 >> 11;
        int tt0 = (m0 & 2047) + wr * 32 + mg * 16 + quad * 4;
        bf16x4 pv = {(__bf16)acc[mg][nt][0], (__bf16)acc[mg][nt][1],
                     (__bf16)acc[mg][nt][2], (__bf16)acc[mg][nt][3]};
        *(bf16x4*)&vt[(size_t)(b * H_ + h) * T_ + tt0] = pv;
      } else {
        __bf16* dh = z == 0 ? qh : kh;
        __bf16* dl = z == 0 ? ql : kl;
#pragma unroll
        for (int reg = 0; reg < 4; ++reg) {
          float v = acc[mg][nt][reg];
          __bf16 hi = (__bf16)v;
          dh[(size_t)(r0 + reg) * H_ + h] = hi;
          dl[(size_t)(r0 + reg) * H_ + h] = (__bf16)(v - (float)hi);
        }
      }
    }
  }
}

// ---------------- attention: flash, split-bf16 QK (3-pass), bf16 PV --------
// round-0 structure (two complementary q-halves per block: st=0 -> pi,
// st=1 -> 63-pi, 4 waves each -- balance is INTRA-block, scheduler-proof).
// block mapping b=j&7, pi=j>>3 gives batch<->XCD affinity
// (verified round 1: FETCH 51MB -> 10.6MB). One batch's K/V/Q (~3.5MB)
// fits the XCD's 4MB L2, cutting K/V load latency in the serial chain.
__global__ __launch_bounds__(512, 2) void attn_kernel(
    const __bf16* __restrict__ qh, const __bf16* __restrict__ qlo,
    const __bf16* __restrict__ kh, const __bf16* __restrict__ klo,
    const __bf16* __restrict__ vt, float* __restrict__ out) {
  const int t = threadIdx.x;
  const int wv = t >> 6, st = wv >> 2, cw = wv & 3;
  const int lane = t & 63, l15 = lane & 15, quad = lane >> 4;
  const int j = blockIdx.x, b = j & 7, pi = j >> 3;
  const int qlidx = (st == 0) ? pi : 63 - pi;
  const int t0 = qlidx * 32;
  const int nkt = (qlidx >> 1) + 1;
  __shared__ __align__(16) __bf16 Pbuf[8][32 * 72];
  __shared__ __align__(16) float Obuf[2][32 * 132];
  __shared__ float mlb[2][4][32], llb[2][4][32];
  const size_t qrow0 = (size_t)b * T_ + t0;
  bf16x8 qfh[2][4], qfl[2][4];
#pragma unroll
  for (int mg = 0; mg < 2; ++mg)
#pragma unroll
    for (int ds = 0; ds < 4; ++ds) {
      size_t off = (qrow0 + mg * 16 + l15) * H_ + ds * 32 + quad * 8;
      qfh[mg][ds] = *(const bf16x8*)(qh + off);
      qfl[mg][ds] = *(const bf16x8*)(qlo + off);
    }
  f32x4 O[2][8] = {};
  float ms[2][4], ls[2][4];
#pragma unroll
  for (int mg = 0; mg < 2; ++mg)
#pragma unroll
    for (int reg = 0; reg < 4; ++reg) {
      ms[mg][reg] = -INFINITY;
      ls[mg][reg] = 0.f;
    }
  const __bf16* vtb = vt + (size_t)b * H_ * T_;
  const float scale = 11.313708498984761f;  // sqrt(128); ref multiplies
  for (int kt_i = cw; kt_i < nkt; kt_i += 4) {
    const int kt = kt_i * 64;
    f32x4 S[2][4] = {};
#pragma unroll
    for (int ds = 0; ds < 4; ++ds)
#pragma unroll
      for (int ct = 0; ct < 4; ++ct) {
        size_t koff =
            ((size_t)b * T_ + kt + ct * 16 + l15) * H_ + ds * 32 + quad * 8;
        bf16x8 bh = *(const bf16x8*)(kh + koff);
        bf16x8 bl = *(const bf16x8*)(klo + koff);
#pragma unroll
        for (int mg = 0; mg < 2; ++mg) {
          S[mg][ct] = MFMA(qfh[mg][ds], bh, S[mg][ct]);
          S[mg][ct] = MFMA(qfl[mg][ds], bh, S[mg][ct]);
          S[mg][ct] = MFMA(qfh[mg][ds], bl, S[mg][ct]);
        }
      }
    const bool diag = (kt_i == nkt - 1);
#pragma unroll
    for (int mg = 0; mg < 2; ++mg)
#pragma unroll
      for (int ct = 0; ct < 4; ++ct)
#pragma unroll
        for (int reg = 0; reg < 4; ++reg) {
          float s = S[mg][ct][reg] * scale;
          if (diag && (kt + ct * 16 + l15 > t0 + mg * 16 + quad * 4 + reg))
            s = -1e30f;
          S[mg][ct][reg] = s;
        }
    float al_[2][4];
#pragma unroll
    for (int mg = 0; mg < 2; ++mg)
#pragma unroll
      for (int reg = 0; reg < 4; ++reg) {
        float r = fmaxf(fmaxf(S[mg][0][reg], S[mg][1][reg]),
                        fmaxf(S[mg][2][reg], S[mg][3][reg]));
        r = fmaxf(r, __shfl_xor(r, 1));
        r = fmaxf(r, __shfl_xor(r, 2));
        r = fmaxf(r, __shfl_xor(r, 4));
        r = fmaxf(r, __shfl_xor(r, 8));
        float mn = fmaxf(ms[mg][reg], r);
        float a = __expf(ms[mg][reg] - mn);
        ms[mg][reg] = mn;
        float ps = 0.f;
#pragma unroll
        for (int ct = 0; ct < 4; ++ct) {
          float p = __expf(S[mg][ct][reg] - mn);
          S[mg][ct][reg] = p;
          ps += p;
        }
        ps += __shfl_xor(ps, 1);
        ps += __shfl_xor(ps, 2);
        ps += __shfl_xor(ps, 4);
        ps += __shfl_xor(ps, 8);
        ls[mg][reg] = ls[mg][reg] * a + ps;
        al_[mg][reg] = a;
      }
#pragma unroll
    for (int mg = 0; mg < 2; ++mg)
#pragma unroll
      for (int ht = 0; ht < 8; ++ht)
#pragma unroll
        for (int reg = 0; reg < 4; ++reg) O[mg][ht][reg] *= al_[mg][reg];
#pragma unroll
    for (int mg = 0; mg < 2; ++mg)
#pragma unroll
      for (int ct = 0; ct < 4; ++ct)
#pragma unroll
        for (int reg = 0; reg < 4; ++reg)
          Pbuf[wv][(mg * 16 + quad * 4 + reg) * 72 + ct * 16 + l15] =
              (__bf16)S[mg][ct][reg];
#pragma unroll
    for (int ks = 0; ks < 2; ++ks) {
      bf16x8 pf0 = *(bf16x8*)&Pbuf[wv][(l15)*72 + ks * 32 + quad * 8];
      bf16x8 pf1 = *(bf16x8*)&Pbuf[wv][(16 + l15) * 72 + ks * 32 + quad * 8];
#pragma unroll
      for (int ht = 0; ht < 8; ++ht) {
        bf16x8 vf = *(const bf16x8*)&vtb[(size_t)(ht * 16 + l15) * T_ + kt +
                                         ks * 32 + quad * 8];
        O[0][ht] = MFMA(pf0, vf, O[0][ht]);
        O[1][ht] = MFMA(pf1, vf, O[1][ht]);
      }
    }
  }
  if (l15 == 0) {
#pragma unroll
    for (int mg = 0; mg < 2; ++mg)
#pragma unroll
      for (int reg = 0; reg < 4; ++reg) {
        mlb[st][cw][mg * 16 + quad * 4 + reg] = ms[mg][reg];
        llb[st][cw][mg * 16 + quad * 4 + reg] = ls[mg][reg];
      }
  }
  for (int i = t; i < 2 * 32 * 132; i += 512) ((float*)Obuf)[i] = 0.f;
  __syncthreads();
  float aw[2][4];
#pragma unroll
  for (int mg = 0; mg < 2; ++mg)
#pragma unroll
    for (int reg = 0; reg < 4; ++reg) {
      int row = mg * 16 + quad * 4 + reg;
      float M = fmaxf(fmaxf(mlb[st][0][row], mlb[st][1][row]),
                      fmaxf(mlb[st][2][row], mlb[st][3][row]));
      float L = 0.f;
#pragma unroll
      for (int w = 0; w < 4; ++w)
        L += llb[st][w][row] * __expf(mlb[st][w][row] - M);
      aw[mg][reg] = __expf(ms[mg][reg] - M) / L;
    }
#pragma unroll
  for (int mg = 0; mg < 2; ++mg)
#pragma unroll
    for (int ht = 0; ht < 8; ++ht)
#pragma unroll
      for (int reg = 0; reg < 4; ++reg)
        atomicAdd(&Obuf[st][(mg * 16 + quad * 4 + reg) * 132 + ht * 16 + l15],
                  O[mg][ht][reg] * aw[mg][reg]);
  __syncthreads();
  {
    const int stw = t >> 8, tt = t & 255;
    const int qlw = (stw == 0) ? pi : 63 - pi;
    const size_t obase = ((size_t)b * T_ + qlw * 32) * H_;
#pragma unroll
    for (int i = 0; i < 4; ++i) {
      int f4 = i * 256 + tt;
      int row = f4 >> 5, c = (f4 & 31) << 2;
      *(float4*)&out[obase + (size_t)row * H_ + c] =
          *(float4*)&Obuf[stw][row * 132 + c];
    }
  }
}

extern "C" void kernel_launch(void* const* d_in, const int* in_sizes, int n_in,
                              void* d_out, int out_size, void* d_ws, size_t ws_size,
                              hipStream_t stream) {
  const float* x = (const float*)d_in[0];
  const float* Wq = (const float*)d_in[1];
  const float* Wk = (const float*)d_in[2];
  const float* Wv = (const float*)d_in[3];
  __bf16* ws = (__bf16*)d_ws;
  float* out = (float*)d_out;
  prep_kernel<<<dim3(32, 3), 256, 0, stream>>>(Wq, Wk, Wv, ws + WTH_OFF,
                                               ws + WTL_OFF);
  proj_kernel<<<512, 512, 0, stream>>>(x, ws + WTH_OFF, ws + WTL_OFF,
                                       ws + QH_OFF, ws + QL_OFF, ws + KH_OFF,
                                       ws + KL_OFF, ws + VT_OFF);
  attn_kernel<<<256, 512, 0, stream>>>(ws + QH_OFF, ws + QL_OFF, ws + KH_OFF,
                                       ws + KL_OFF, ws + VT_OFF, out);
}

// Round 9
// 362.021 us; speedup vs baseline: 1.3509x; 1.0632x over previous
//
#include <hip/hip_runtime.h>
#include <math.h>

#define B_ 8
#define T_ 2048
#define D_ 2048
#define H_ 128
#define M_ (B_ * T_)

typedef __bf16 bf16x8 __attribute__((ext_vector_type(8)));
typedef __bf16 bf16x4 __attribute__((ext_vector_type(4)));
typedef float f32x4 __attribute__((ext_vector_type(4)));

#define MFMA(a, b, c) __builtin_amdgcn_mfma_f32_16x16x32_bf16(a, b, c, 0, 0, 0)

// ws layout (bf16 elements)
#define QH_OFF 0
#define QL_OFF (1 * 2097152)  // M_*H_
#define KH_OFF (2 * 2097152)
#define KL_OFF (3 * 2097152)
#define VT_OFF (4 * 2097152)        // vt[b][h][t]
#define WTH_OFF (5 * 2097152)       // wpk_hi[g][ks][lane][8] fragment-packed
#define WTL_OFF (WTH_OFF + 786432)  // 3*128*2048

// global_load_lds: per-lane global src, wave-uniform LDS dst, 16B/lane
#define GL_LDS16(gp, lp)                                      \
  __builtin_amdgcn_global_load_lds(                           \
      (const __attribute__((address_space(1))) void*)(gp),    \
      (__attribute__((address_space(3))) void*)(lp), 16, 0, 0)

// ---------------- prep: W[k][n] fp32 -> fragment-packed hi/lo bf16 ---------
// (round-7 version, verified correct.) Packed layout: n-group g = n>>4
// (24 groups), kstep s: the 64-lane B-fragment is contiguous at elem
// ((g*64+s)*64 + lane)*8, lane = quad*16+l15, holding wt[16g+l15][32s+8q+j].
__global__ __launch_bounds__(256) void prep_kernel(
    const float* __restrict__ Wq, const float* __restrict__ Wk,
    const float* __restrict__ Wv, __bf16* __restrict__ wpk_hi,
    __bf16* __restrict__ wpk_lo) {
  const int z = blockIdx.y;
  const int k0 = blockIdx.x * 64;
  const float* W = z == 0 ? Wq : z == 1 ? Wk : Wv;
  __shared__ float tile[64][132];
  const int t = threadIdx.x;
#pragma unroll
  for (int it = 0; it < 8; ++it) {
    int f4 = it * 256 + t;  // 2048 float4 = 64 rows x 32
    int row = f4 >> 5, c = (f4 & 31) << 2;
    *(float4*)&tile[row][c] = *(const float4*)&W[(size_t)(k0 + row) * H_ + c];
  }
  __syncthreads();
  int n = t >> 1, kh = (t & 1) << 5;  // row n (0..127), k-base k0+kh
  __bf16 h[32], l[32];
#pragma unroll
  for (int kk = 0; kk < 32; ++kk) {
    float x = tile[kh + kk][n];
    __bf16 hi = (__bf16)x;
    h[kk] = hi;
    l[kk] = (__bf16)(x - (float)hi);
  }
  const int nf = z * H_ + n;  // 0..383
  const int g = nf >> 4, l15 = nf & 15;
  const int s = (k0 + kh) >> 5;
#pragma unroll
  for (int c = 0; c < 4; ++c) {  // chunk c -> quad c
    size_t dst = ((size_t)(g * 64 + s) * 64 + c * 16 + l15) * 8;
    *(bf16x8*)&wpk_hi[dst] = *(bf16x8*)&h[c * 8];
    *(bf16x8*)&wpk_lo[dst] = *(bf16x8*)&l[c * 8];
  }
}

// ---------------- proj: T3 2-phase, gload_lds W, dbuf LDS, 1 barrier/kstep -
// v8: 512 blocks x 512 thr (8 waves). Block = 64m x 192n (n-half = bi&1 ->
// XCD parity, W-half L2-resident). Wave = 32m x 48n, 18 MFMA/kstep.
// R5-R8 triangulation: no single knob (occupancy/DS-volume/prefetch-depth)
// moved the 132us floor -> the cost is the BUNDLE: 2 full-drain barriers per
// kstep + staging-write bank conflicts + B-frag repack VALU. This round
// ports the T3 minimal 2-phase recipe: W staged by global_load_lds (width
// 16, 3/wave/kstep, zero ds_writes, zero repack) from the packed layout
// into lane-linear LDS fragments (conflict-free b128 reads); X+W double-
// buffered; ONE raw s_barrier per kstep with counted vmcnt(1) that never
// drains the depth-2 X register prefetch (xA/xB static names, rule #20).
// sched_barrier(0) fences per rule #18; one between gloads and the X load
// so the X load is provably the newest VMEM op at vmcnt(1).
// Numerics bit-identical to R5 (same fragment values, same MFMA order).
#define XSTR 72  // X row-pair stride (32 hi | 32 lo | 8 pad) = 144 B

#define XCONV(RW, NB)                                                       \
  {                                                                         \
    __bf16 h0 = (__bf16)RW.x, h1 = (__bf16)RW.y, h2 = (__bf16)RW.z,         \
           h3 = (__bf16)RW.w;                                               \
    bf16x4 hv = {h0, h1, h2, h3};                                           \
    bf16x4 lv = {(__bf16)(RW.x - (float)h0), (__bf16)(RW.y - (float)h1),    \
                 (__bf16)(RW.z - (float)h2), (__bf16)(RW.w - (float)h3)};   \
    *(bf16x4*)&Xs[NB][xm * XSTR + xk] = hv;                                 \
    *(bf16x4*)&Xs[NB][xm * XSTR + 32 + xk] = lv;                            \
  }

#define COMPUTE(CUR)                                                        \
  {                                                                         \
    bf16x8 ah[2], al[2];                                                    \
    _Pragma("unroll") for (int mg = 0; mg < 2; ++mg) {                      \
      ah[mg] = *(bf16x8*)&Xs[CUR][(wr * 32 + mg * 16 + l15) * XSTR + q8];   \
      al[mg] =                                                              \
          *(bf16x8*)&Xs[CUR][(wr * 32 + mg * 16 + l15) * XSTR + 32 + q8];   \
    }                                                                       \
    _Pragma("unroll") for (int nt = 0; nt < 3; ++nt) {                      \
      const int g = wc * 3 + nt;                                            \
      bf16x8 bh = *(bf16x8*)&Wf[CUR][g * 512 + lane * 8];                   \
      bf16x8 bl = *(bf16x8*)&Wf[CUR][6144 + g * 512 + lane * 8];            \
      _Pragma("unroll") for (int mg = 0; mg < 2; ++mg) {                    \
        acc[mg][nt] = MFMA(ah[mg], bh, acc[mg][nt]);                        \
        acc[mg][nt] = MFMA(al[mg], bh, acc[mg][nt]);                        \
        acc[mg][nt] = MFMA(ah[mg], bl, acc[mg][nt]);                        \
      }                                                                     \
    }                                                                       \
  }

#define PSTEP(KS, RW, RL)                                                   \
  {                                                                         \
    const int nb_ = ((KS)&1) ^ 1;                                           \
    _Pragma("unroll") for (int i = 0; i < 3; ++i)                           \
        GL_LDS16(gsrc[i] + ((KS) + 1) * 512, ldst0[i] + nb_ * 12288);       \
    __builtin_amdgcn_sched_barrier(0); /* gloads older than X load */       \
    RL = *(const float4*)(xgp + ((KS) + 2) * 32);                           \
    XCONV(RW, nb_);                                                         \
    COMPUTE((KS)&1);                                                        \
    asm volatile("s_waitcnt vmcnt(1) lgkmcnt(0)" ::: "memory");             \
    __builtin_amdgcn_sched_barrier(0);                                      \
    __builtin_amdgcn_s_barrier();                                           \
    __builtin_amdgcn_sched_barrier(0);                                      \
  }

__global__ __launch_bounds__(512, 4) void proj_kernel(
    const float* __restrict__ X, const __bf16* __restrict__ wpk_hi,
    const __bf16* __restrict__ wpk_lo, __bf16* __restrict__ qh,
    __bf16* __restrict__ ql, __bf16* __restrict__ kh,
    __bf16* __restrict__ kl, __bf16* __restrict__ vt) {
  __shared__ __align__(16) __bf16 Wf[2][12288];      // 49152 B (dbuf frags)
  __shared__ __align__(16) __bf16 Xs[2][64 * XSTR];  // 18432 B (dbuf)
  const int t = threadIdx.x;
  const int wv = t >> 6, lane = t & 63;
  const int l15 = lane & 15, quad = lane >> 4, q8 = quad * 8;
  const int bi = blockIdx.x;
  const int m0 = (bi >> 1) * 64;
  const int nbase = (bi & 1) * 192;
  const int wr = wv >> 2, wc = wv & 3;  // wave tile: 32m x 48n
  // X staging map: 64 rows x 8 col-quads (one float4/thread)
  const int xm = t >> 3, xk = (t & 7) << 2;
  const float* xgp = X + (size_t)(m0 + xm) * D_ + xk;
  // W staging: wave wv owns fragments f = wv*3 + i, f in [0,24):
  // sel = f/12 (hi|lo), gl = f%12; global group gg = nbase/16 + gl.
  const __bf16* gsrc[3];
  __bf16* ldst0[3];
#pragma unroll
  for (int i = 0; i < 3; ++i) {
    int f = wv * 3 + i;
    int sel = f >= 12;
    int gl = f - sel * 12;
    int gg = (nbase >> 4) + gl;
    gsrc[i] = (sel ? wpk_lo : wpk_hi) + (size_t)gg * 32768 + (size_t)lane * 8;
    ldst0[i] = &Wf[0][sel * 6144 + gl * 512];
  }
  f32x4 acc[2][3] = {};
  // prologue: stage kstep 0 (W via gload_lds, X via reg+convert), load X(1)
  {
    float4 x0 = *(const float4*)xgp;
#pragma unroll
    for (int i = 0; i < 3; ++i) GL_LDS16(gsrc[i], ldst0[i]);
    XCONV(x0, 0);
  }
  float4 xA = *(const float4*)(xgp + 32);  // X(1)
  float4 xB;
  asm volatile("s_waitcnt vmcnt(0) lgkmcnt(0)" ::: "memory");
  __builtin_amdgcn_sched_barrier(0);
  __builtin_amdgcn_s_barrier();
  __builtin_amdgcn_sched_barrier(0);
  // main loop: ks = 0..61 (paired for static xA/xB renaming)
  for (int ks2 = 0; ks2 < 62; ks2 += 2) {
    PSTEP(ks2, xA, xB);
    PSTEP(ks2 + 1, xB, xA);
  }
  // ks = 62: stage W(63) + X(63); no further X load -> full drain
  {
#pragma unroll
    for (int i = 0; i < 3; ++i)
      GL_LDS16(gsrc[i] + 63 * 512, ldst0[i] + 12288);
    XCONV(xA, 1);
    COMPUTE(0);
    asm volatile("s_waitcnt vmcnt(0) lgkmcnt(0)" ::: "memory");
    __builtin_amdgcn_sched_barrier(0);
    __builtin_amdgcn_s_barrier();
    __builtin_amdgcn_sched_barrier(0);
  }
  COMPUTE(1);  // ks = 63
  // epilogue (C/D: col = l15 -> n, row = quad*4+reg -> m)
#pragma unroll
  for (int nt = 0; nt < 3; ++nt) {
    int ncb = nbase + wc * 48 + nt * 16;  // 16-aligned, within one z
    int z = ncb >> 7;
    int h = (ncb & 127) + l15;
#pragma unroll
    for (int mg = 0; mg < 2; ++mg) {
      int r0 = m0 + wr * 32 + mg * 16 + quad * 4;
      if (z == 2) {
        int b = m0 >> 11;
        int tt0 = (m0 & 2047) + wr * 32 + mg * 16 + quad * 4;
        bf16x4 pv = {(__bf16)acc[mg][nt][0], (__bf16)acc[mg][nt][1],
                     (__bf16)acc[mg][nt][2], (__bf16)acc[mg][nt][3]};
        *(bf16x4*)&vt[(size_t)(b * H_ + h) * T_ + tt0] = pv;
      } else {
        __bf16* dh = z == 0 ? qh : kh;
        __bf16* dl = z == 0 ? ql : kl;
#pragma unroll
        for (int reg = 0; reg < 4; ++reg) {
          float v = acc[mg][nt][reg];
          __bf16 hi = (__bf16)v;
          dh[(size_t)(r0 + reg) * H_ + h] = hi;
          dl[(size_t)(r0 + reg) * H_ + h] = (__bf16)(v - (float)hi);
        }
      }
    }
  }
}

// ---------------- attention: flash, split-bf16 QK (3-pass), bf16 PV --------
// round-0 structure (two complementary q-halves per block: st=0 -> pi,
// st=1 -> 63-pi, 4 waves each -- balance is INTRA-block, scheduler-proof).
// block mapping b=j&7, pi=j>>3 gives batch<->XCD affinity
// (verified round 1: FETCH 51MB -> 10.6MB). One batch's K/V/Q (~3.5MB)
// fits the XCD's 4MB L2, cutting K/V load latency in the serial chain.
__global__ __launch_bounds__(512, 2) void attn_kernel(
    const __bf16* __restrict__ qh, const __bf16* __restrict__ qlo,
    const __bf16* __restrict__ kh, const __bf16* __restrict__ klo,
    const __bf16* __restrict__ vt, float* __restrict__ out) {
  const int t = threadIdx.x;
  const int wv = t >> 6, st = wv >> 2, cw = wv & 3;
  const int lane = t & 63, l15 = lane & 15, quad = lane >> 4;
  const int j = blockIdx.x, b = j & 7, pi = j >> 3;
  const int qlidx = (st == 0) ? pi : 63 - pi;
  const int t0 = qlidx * 32;
  const int nkt = (qlidx >> 1) + 1;
  __shared__ __align__(16) __bf16 Pbuf[8][32 * 72];
  __shared__ __align__(16) float Obuf[2][32 * 132];
  __shared__ float mlb[2][4][32], llb[2][4][32];
  const size_t qrow0 = (size_t)b * T_ + t0;
  bf16x8 qfh[2][4], qfl[2][4];
#pragma unroll
  for (int mg = 0; mg < 2; ++mg)
#pragma unroll
    for (int ds = 0; ds < 4; ++ds) {
      size_t off = (qrow0 + mg * 16 + l15) * H_ + ds * 32 + quad * 8;
      qfh[mg][ds] = *(const bf16x8*)(qh + off);
      qfl[mg][ds] = *(const bf16x8*)(qlo + off);
    }
  f32x4 O[2][8] = {};
  float ms[2][4], ls[2][4];
#pragma unroll
  for (int mg = 0; mg < 2; ++mg)
#pragma unroll
    for (int reg = 0; reg < 4; ++reg) {
      ms[mg][reg] = -INFINITY;
      ls[mg][reg] = 0.f;
    }
  const __bf16* vtb = vt + (size_t)b * H_ * T_;
  const float scale = 11.313708498984761f;  // sqrt(128); ref multiplies
  for (int kt_i = cw; kt_i < nkt; kt_i += 4) {
    const int kt = kt_i * 64;
    f32x4 S[2][4] = {};
#pragma unroll
    for (int ds = 0; ds < 4; ++ds)
#pragma unroll
      for (int ct = 0; ct < 4; ++ct) {
        size_t koff =
            ((size_t)b * T_ + kt + ct * 16 + l15) * H_ + ds * 32 + quad * 8;
        bf16x8 bh = *(const bf16x8*)(kh + koff);
        bf16x8 bl = *(const bf16x8*)(klo + koff);
#pragma unroll
        for (int mg = 0; mg < 2; ++mg) {
          S[mg][ct] = MFMA(qfh[mg][ds], bh, S[mg][ct]);
          S[mg][ct] = MFMA(qfl[mg][ds], bh, S[mg][ct]);
          S[mg][ct] = MFMA(qfh[mg][ds], bl, S[mg][ct]);
        }
      }
    const bool diag = (kt_i == nkt - 1);
#pragma unroll
    for (int mg = 0; mg < 2; ++mg)
#pragma unroll
      for (int ct = 0; ct < 4; ++ct)
#pragma unroll
        for (int reg = 0; reg < 4; ++reg) {
          float s = S[mg][ct][reg] * scale;
          if (diag && (kt + ct * 16 + l15 > t0 + mg * 16 + quad * 4 + reg))
            s = -1e30f;
          S[mg][ct][reg] = s;
        }
    float al_[2][4];
#pragma unroll
    for (int mg = 0; mg < 2; ++mg)
#pragma unroll
      for (int reg = 0; reg < 4; ++reg) {
        float r = fmaxf(fmaxf(S[mg][0][reg], S[mg][1][reg]),
                        fmaxf(S[mg][2][reg], S[mg][3][reg]));
        r = fmaxf(r, __shfl_xor(r, 1));
        r = fmaxf(r, __shfl_xor(r, 2));
        r = fmaxf(r, __shfl_xor(r, 4));
        r = fmaxf(r, __shfl_xor(r, 8));
        float mn = fmaxf(ms[mg][reg], r);
        float a = __expf(ms[mg][reg] - mn);
        ms[mg][reg] = mn;
        float ps = 0.f;
#pragma unroll
        for (int ct = 0; ct < 4; ++ct) {
          float p = __expf(S[mg][ct][reg] - mn);
          S[mg][ct][reg] = p;
          ps += p;
        }
        ps += __shfl_xor(ps, 1);
        ps += __shfl_xor(ps, 2);
        ps += __shfl_xor(ps, 4);
        ps += __shfl_xor(ps, 8);
        ls[mg][reg] = ls[mg][reg] * a + ps;
        al_[mg][reg] = a;
      }
#pragma unroll
    for (int mg = 0; mg < 2; ++mg)
#pragma unroll
      for (int ht = 0; ht < 8; ++ht)
#pragma unroll
        for (int reg = 0; reg < 4; ++reg) O[mg][ht][reg] *= al_[mg][reg];
#pragma unroll
    for (int mg = 0; mg < 2; ++mg)
#pragma unroll
      for (int ct = 0; ct < 4; ++ct)
#pragma unroll
        for (int reg = 0; reg < 4; ++reg)
          Pbuf[wv][(mg * 16 + quad * 4 + reg) * 72 + ct * 16 + l15] =
              (__bf16)S[mg][ct][reg];
#pragma unroll
    for (int ks = 0; ks < 2; ++ks) {
      bf16x8 pf0 = *(bf16x8*)&Pbuf[wv][(l15)*72 + ks * 32 + quad * 8];
      bf16x8 pf1 = *(bf16x8*)&Pbuf[wv][(16 + l15) * 72 + ks * 32 + quad * 8];
#pragma unroll
      for (int ht = 0; ht < 8; ++ht) {
        bf16x8 vf = *(const bf16x8*)&vtb[(size_t)(ht * 16 + l15) * T_ + kt +
                                         ks * 32 + quad * 8];
        O[0][ht] = MFMA(pf0, vf, O[0][ht]);
        O[1][ht] = MFMA(pf1, vf, O[1][ht]);
      }
    }
  }
  if (l15 == 0) {
#pragma unroll
    for (int mg = 0; mg < 2; ++mg)
#pragma unroll
      for (int reg = 0; reg < 4; ++reg) {
        mlb[st][cw][mg * 16 + quad * 4 + reg] = ms[mg][reg];
        llb[st][cw][mg * 16 + quad * 4 + reg] = ls[mg][reg];
      }
  }
  for (int i = t; i < 2 * 32 * 132; i += 512) ((float*)Obuf)[i] = 0.f;
  __syncthreads();
  float aw[2][4];
#pragma unroll
  for (int mg = 0; mg < 2; ++mg)
#pragma unroll
    for (int reg = 0; reg < 4; ++reg) {
      int row = mg * 16 + quad * 4 + reg;
      float M = fmaxf(fmaxf(mlb[st][0][row], mlb[st][1][row]),
                      fmaxf(mlb[st][2][row], mlb[st][3][row]));
      float L = 0.f;
#pragma unroll
      for (int w = 0; w < 4; ++w)
        L += llb[st][w][row] * __expf(mlb[st][w][row] - M);
      aw[mg][reg] = __expf(ms[mg][reg] - M) / L;
    }
#pragma unroll
  for (int mg = 0; mg < 2; ++mg)
#pragma unroll
    for (int ht = 0; ht < 8; ++ht)
#pragma unroll
      for (int reg = 0; reg < 4; ++reg)
        atomicAdd(&Obuf[st][(mg * 16 + quad * 4 + reg) * 132 + ht * 16 + l15],
                  O[mg][ht][reg] * aw[mg][reg]);
  __syncthreads();
  {
    const int stw = t >> 8, tt = t & 255;
    const int qlw = (stw == 0) ? pi : 63 - pi;
    const size_t obase = ((size_t)b * T_ + qlw * 32) * H_;
#pragma unroll
    for (int i = 0; i < 4; ++i) {
      int f4 = i * 256 + tt;
      int row = f4 >> 5, c = (f4 & 31) << 2;
      *(float4*)&out[obase + (size_t)row * H_ + c] =
          *(float4*)&Obuf[stw][row * 132 + c];
    }
  }
}

extern "C" void kernel_launch(void* const* d_in, const int* in_sizes, int n_in,
                              void* d_out, int out_size, void* d_ws, size_t ws_size,
                              hipStream_t stream) {
  const float* x = (const float*)d_in[0];
  const float* Wq = (const float*)d_in[1];
  const float* Wk = (const float*)d_in[2];
  const float* Wv = (const float*)d_in[3];
  __bf16* ws = (__bf16*)d_ws;
  float* out = (float*)d_out;
  prep_kernel<<<dim3(32, 3), 256, 0, stream>>>(Wq, Wk, Wv, ws + WTH_OFF,
                                               ws + WTL_OFF);
  proj_kernel<<<512, 512, 0, stream>>>(x, ws + WTH_OFF, ws + WTL_OFF,
                                       ws + QH_OFF, ws + QL_OFF, ws + KH_OFF,
                                       ws + KL_OFF, ws + VT_OFF);
  attn_kernel<<<256, 512, 0, stream>>>(ws + QH_OFF, ws + QL_OFF, ws + KH_OFF,
                                       ws + KL_OFF, ws + VT_OFF, out);
}